// Round 8
// baseline (87.178 us; speedup 1.0000x reference)
//
#include <hip/hip_runtime.h>
#include <hip/hip_fp8.h>
#include <math.h>

// ContrastiveLoss — x (8,128,16,8,8) fp32 (4 MB).
// feats[n,f] = x[b*131072 + f*1024 + r], n=(b<<10)|r, N=8192, F=128.
// loss = 10 + ln( sum_{i!=j} exp(10*dot(x̂_i,x̂_j) - 10) )   (unit rows => s<=10)
//
// Round 8: fp8 gram with CONTIGUOUS tile runs — 1376 blocks x exactly 6 tiles
// (8256 = 1376*6). I is constant within most runs -> A-fragments register-
// resident, 4 (not 8) dwordx4 per wave per tile (~135 MB total fragment
// traffic, down 2x from R7). Incremental (I,J) advance, no per-tile decode.
// HW fp8 convert in norm (v_cvt_pk_fp8_f32), HW exp2 in epilogue.
//
// fp8 swizzled layout (verified R7, absmax 0): row-group rg=n>>4 (16 rows,
// 2KB). 16B chunk (t8*64 + q*16 + r) holds bytes[half*8+j] =
// x̂[row r][k = t8*64 + half*32 + q*8 + j] — lane q*16+r's A/B fragments for
// k-steps 2*t8 (low 8B) / 2*t8+1 (high 8B) of mfma_f32_16x16x32_fp8_fp8.
// C/D layout dtype-independent: col=lane&15, row=(lane>>4)*4+reg.
//
// ws: partials float[1376] @0; Xs fp8[8192*128] @131072 (1MB).

#define NTILE 8256   // 128*129/2 upper-triangle 64x64 tiles
#define NPBLK 1376   // 8256 / 6 tiles per block

typedef __attribute__((ext_vector_type(4))) float f32x4;

#if __has_builtin(__builtin_amdgcn_exp2f)
#define EXP2F(x) __builtin_amdgcn_exp2f(x)
#else
#define EXP2F(x) exp2f(x)
#endif

__device__ inline unsigned int pk_fp8(float f0, float f1, float f2, float f3) {
#if __has_builtin(__builtin_amdgcn_cvt_pk_fp8_f32)
    unsigned int r = 0;
    r = __builtin_amdgcn_cvt_pk_fp8_f32(f0, f1, r, false);  // bytes 0,1
    r = __builtin_amdgcn_cvt_pk_fp8_f32(f2, f3, r, true);   // bytes 2,3
    return r;
#else
    union { unsigned char b[4]; unsigned int u; } v;
    v.b[0] = __hip_fp8_e4m3(f0).__x; v.b[1] = __hip_fp8_e4m3(f1).__x;
    v.b[2] = __hip_fp8_e4m3(f2).__x; v.b[3] = __hip_fp8_e4m3(f3).__x;
    return v.u;
#endif
}

// ---------------------------------------------------------------------------
// Kernel 1: normalize + fp8 swizzle. Block = 32 rows (2 row-groups).
// Phase 1: coalesced read of x (each element once) into LDS (pad 33).
// Phase 2: one 16B output chunk per thread (HW packed fp8 convert).
// ---------------------------------------------------------------------------
__global__ __launch_bounds__(256)
void normalize_kernel(const float* __restrict__ x, unsigned char* __restrict__ Xs) {
    __shared__ float ldsf[128][33];
    __shared__ float ssred[8][32];
    __shared__ float invs[32];
    const int tid = threadIdx.x;
    const int b  = blockIdx.x >> 5;
    const int r0 = (blockIdx.x & 31) * 32;
    const int rl = tid & 31, fp = tid >> 5;       // row-in-block, f-slot
    const float* px = x + b * 131072 + r0 + rl;
    float ss = 0.f;
#pragma unroll
    for (int j = 0; j < 16; ++j) {
        int f = fp * 16 + j;
        float v = px[f * 1024];
        ldsf[f][rl] = v;
        ss = fmaf(v, v, ss);
    }
    ssred[fp][rl] = ss;
    __syncthreads();
    if (tid < 32) {
        float s = 0.f;
#pragma unroll
        for (int k = 0; k < 8; ++k) s += ssred[k][tid];
        invs[tid] = 1.0f / fmaxf(sqrtf(s), 1e-12f);
    }
    __syncthreads();
    {   // one 16B chunk per thread, consecutive tid -> consecutive chunks
        const int c   = tid;
        const int rgl = c >> 7;                   // local row-group 0..1
        const int cc  = c & 127;                  // chunk within row-group
        const int t8  = (cc >> 6) & 1, q = (cc >> 4) & 3, r = cc & 15;
        const int row = rgl * 16 + r;             // local row 0..31
        const float inv = invs[row];
        union { unsigned int w[4]; int4 v; } u;
#pragma unroll
        for (int half = 0; half < 2; ++half) {
            const int k0 = t8 * 64 + half * 32 + q * 8;
            u.w[half * 2 + 0] = pk_fp8(ldsf[k0 + 0][row] * inv, ldsf[k0 + 1][row] * inv,
                                       ldsf[k0 + 2][row] * inv, ldsf[k0 + 3][row] * inv);
            u.w[half * 2 + 1] = pk_fp8(ldsf[k0 + 4][row] * inv, ldsf[k0 + 5][row] * inv,
                                       ldsf[k0 + 6][row] * inv, ldsf[k0 + 7][row] * inv);
        }
        const int rgg = blockIdx.x * 2 + rgl;     // global row-group
        ((int4*)Xs)[rgg * 128 + cc] = u.v;
    }
}

// ---------------------------------------------------------------------------
// Kernel 2: persistent gram, contiguous runs. Block k: tiles 6k..6k+5.
// Wave w: A rgs (w&1)*2..+1, B rgs (w>>1)*2..+1 of the 64x64 tile.
// A reloaded only when I changes (most runs: once). 4 B-loads/tile/wave.
// No barriers in the loop; per-thread wsum; one block reduce at the end.
// ---------------------------------------------------------------------------
__global__ __launch_bounds__(256, 6)
void gram_lse_kernel(const int4* __restrict__ Xs, float* __restrict__ partials) {
    const int bk = blockIdx.x;
    const int tid = threadIdx.x;
    const int lane = tid & 63, w = tid >> 6;
    const int ga = (w & 1) * 2;                  // A rg offset within tile
    const int gb = (w >> 1) * 2;                 // B rg offset within tile
    const int quad = lane >> 4, colL = lane & 15;
    const float C = 14.426950408889634f;         // 10*log2(e)

    // decode first tile of the run (once per block)
    int L = bk * 6, I = 0;
    while (L >= 128 - I) { L -= 128 - I; ++I; }
    int J = I + L;

    float wsum = 0.f;
    int Icur = -1;
    int4 av[2][2];                               // A fragments [g][t8]
#pragma unroll
    for (int s = 0; s < 6; ++s) {
        if (I != Icur) {
            const int argb = I * 4 + ga;
#pragma unroll
            for (int g = 0; g < 2; ++g)
#pragma unroll
                for (int t8 = 0; t8 < 2; ++t8)
                    av[g][t8] = Xs[(argb + g) * 128 + t8 * 64 + lane];
            Icur = I;
        }
        const int brgb = J * 4 + gb;
        int4 bv[2][2];
#pragma unroll
        for (int g = 0; g < 2; ++g)
#pragma unroll
            for (int t8 = 0; t8 < 2; ++t8)
                bv[g][t8] = Xs[(brgb + g) * 128 + t8 * 64 + lane];

        f32x4 acc[2][2];
#pragma unroll
        for (int i = 0; i < 2; ++i)
#pragma unroll
            for (int j = 0; j < 2; ++j) acc[i][j] = (f32x4){0.f, 0.f, 0.f, 0.f};
#pragma unroll
        for (int t = 0; t < 4; ++t) {            // K-steps of 32
            long aL[2], bL[2];
#pragma unroll
            for (int g = 0; g < 2; ++g) {
                aL[g] = ((const long*)&av[g][t >> 1])[t & 1];
                bL[g] = ((const long*)&bv[g][t >> 1])[t & 1];
            }
#pragma unroll
            for (int i = 0; i < 2; ++i)
#pragma unroll
                for (int j = 0; j < 2; ++j)
                    acc[i][j] = __builtin_amdgcn_mfma_f32_16x16x32_fp8_fp8(
                        aL[i], bL[j], acc[i][j], 0, 0, 0);
        }

        // C/D: col=lane&15, row=(lane>>4)*4+reg (dtype-independent, verified)
        const bool diagT = (I == J);
        float lsum = 0.f;
#pragma unroll
        for (int i = 0; i < 2; ++i) {
            const int rbase = (ga + i) * 16 + quad * 4;   // row within tile
#pragma unroll
            for (int j = 0; j < 2; ++j) {
                const int cbase = (gb + j) * 16 + colL;   // col within tile
#pragma unroll
                for (int g = 0; g < 4; ++g) {
                    if (diagT && (rbase + g == cbase)) continue;
                    lsum += EXP2F(fmaf(C, acc[i][j][g], -C));
                }
            }
        }
        wsum += diagT ? lsum : 2.0f * lsum;      // symmetry weight

        if (++J == 128) { ++I; J = I; }          // next tile in the run
    }

#pragma unroll
    for (int o = 32; o > 0; o >>= 1) wsum += __shfl_down(wsum, o, 64);
    __shared__ float red[4];
    if (lane == 0) red[w] = wsum;
    __syncthreads();
    if (tid == 0) partials[bk] = red[0] + red[1] + red[2] + red[3];
}

// ---------------------------------------------------------------------------
// Kernel 3: out = 10 + ln(sum of 1376 partials), f64 accumulation.
// ---------------------------------------------------------------------------
__global__ __launch_bounds__(256)
void final_kernel(const float* __restrict__ partials, float* __restrict__ out) {
    double s = 0.0;
    for (int i = threadIdx.x; i < NPBLK; i += 256) s += (double)partials[i];
#pragma unroll
    for (int o = 32; o > 0; o >>= 1) s += __shfl_down(s, o, 64);
    __shared__ double red[4];
    if ((threadIdx.x & 63) == 0) red[threadIdx.x >> 6] = s;
    __syncthreads();
    if (threadIdx.x == 0)
        out[0] = (float)(10.0 + log(red[0] + red[1] + red[2] + red[3]));
}

extern "C" void kernel_launch(void* const* d_in, const int* in_sizes, int n_in,
                              void* d_out, int out_size, void* d_ws, size_t ws_size,
                              hipStream_t stream) {
    const float* x = (const float*)d_in[0];
    float* out = (float*)d_out;
    float* partials = (float*)d_ws;                         // 1376 floats
    unsigned char* Xs = (unsigned char*)d_ws + 131072;      // 1MB fp8 X̂

    normalize_kernel<<<256, 256, 0, stream>>>(x, Xs);
    gram_lse_kernel<<<NPBLK, 256, 0, stream>>>((const int4*)Xs, partials);
    final_kernel<<<1, 256, 0, stream>>>(partials, out);
}

// Round 9
// 72.353 us; speedup vs baseline: 1.2049x; 1.2049x over previous
//
#include <hip/hip_runtime.h>
#include <hip/hip_fp8.h>
#include <math.h>

// ContrastiveLoss — x (8,128,16,8,8) fp32 (4 MB).
// feats[n,f] = x[b*131072 + f*1024 + r], n=(b<<10)|r, N=8192, F=128.
// loss = 10 + ln( sum_{i!=j} exp(10*dot(x̂_i,x̂_j) - 10) )   (unit rows => s<=10)
//
// Round 9: explicit software-pipelined fp8 gram. 1376 blocks x 6 contiguous
// tiles; per-block tile list precomputed; B fragments TRIPLE-buffered with
// 2-deep prefetch; A register-resident per row-run; __launch_bounds__(256,4)
// (~128 VGPR) so the pipeline buffers actually stay in registers (R7/R8's
// (256,6) ~84-VGPR budget blocked compiler pipelining).
// Rationale: R1/R3 counters imply effective gfxclk ~500-800 MHz (DVFS) —
// cycles are the only lever; the remaining big cycle block is un-hidden
// per-tile load-use latency.
//
// fp8 swizzled layout (verified R7/R8, absmax 0): row-group rg=n>>4 (16 rows,
// 2KB). 16B chunk (t8*64 + q*16 + r) holds bytes[half*8+j] =
// x̂[row r][k = t8*64 + half*32 + q*8 + j] — lane q*16+r's A/B fragments for
// k-steps 2*t8 (low 8B) / 2*t8+1 (high 8B) of mfma_f32_16x16x32_fp8_fp8.
// C/D layout dtype-independent: col=lane&15, row=(lane>>4)*4+reg.
//
// ws: partials float[1376] @0; Xs fp8[8192*128] @131072 (1MB).

#define NTILE 8256   // 128*129/2 upper-triangle 64x64 tiles
#define NPBLK 1376   // 8256 / 6 tiles per block

typedef __attribute__((ext_vector_type(4))) float f32x4;

#if __has_builtin(__builtin_amdgcn_exp2f)
#define EXP2F(x) __builtin_amdgcn_exp2f(x)
#else
#define EXP2F(x) exp2f(x)
#endif

__device__ inline unsigned int pk_fp8(float f0, float f1, float f2, float f3) {
#if __has_builtin(__builtin_amdgcn_cvt_pk_fp8_f32)
    unsigned int r = 0;
    r = __builtin_amdgcn_cvt_pk_fp8_f32(f0, f1, r, false);  // bytes 0,1
    r = __builtin_amdgcn_cvt_pk_fp8_f32(f2, f3, r, true);   // bytes 2,3
    return r;
#else
    union { unsigned char b[4]; unsigned int u; } v;
    v.b[0] = __hip_fp8_e4m3(f0).__x; v.b[1] = __hip_fp8_e4m3(f1).__x;
    v.b[2] = __hip_fp8_e4m3(f2).__x; v.b[3] = __hip_fp8_e4m3(f3).__x;
    return v.u;
#endif
}

// ---------------------------------------------------------------------------
// Kernel 1: normalize + fp8 swizzle. Block = 32 rows (2 row-groups).
// Phase 1: coalesced read of x (each element once) into LDS (pad 33).
// Phase 2: one 16B output chunk per thread (HW packed fp8 convert).
// ---------------------------------------------------------------------------
__global__ __launch_bounds__(256)
void normalize_kernel(const float* __restrict__ x, unsigned char* __restrict__ Xs) {
    __shared__ float ldsf[128][33];
    __shared__ float ssred[8][32];
    __shared__ float invs[32];
    const int tid = threadIdx.x;
    const int b  = blockIdx.x >> 5;
    const int r0 = (blockIdx.x & 31) * 32;
    const int rl = tid & 31, fp = tid >> 5;       // row-in-block, f-slot
    const float* px = x + b * 131072 + r0 + rl;
    float ss = 0.f;
#pragma unroll
    for (int j = 0; j < 16; ++j) {
        int f = fp * 16 + j;
        float v = px[f * 1024];
        ldsf[f][rl] = v;
        ss = fmaf(v, v, ss);
    }
    ssred[fp][rl] = ss;
    __syncthreads();
    if (tid < 32) {
        float s = 0.f;
#pragma unroll
        for (int k = 0; k < 8; ++k) s += ssred[k][tid];
        invs[tid] = 1.0f / fmaxf(sqrtf(s), 1e-12f);
    }
    __syncthreads();
    {   // one 16B chunk per thread, consecutive tid -> consecutive chunks
        const int c   = tid;
        const int rgl = c >> 7;                   // local row-group 0..1
        const int cc  = c & 127;                  // chunk within row-group
        const int t8  = (cc >> 6) & 1, q = (cc >> 4) & 3, r = cc & 15;
        const int row = rgl * 16 + r;             // local row 0..31
        const float inv = invs[row];
        union { unsigned int w[4]; int4 v; } u;
#pragma unroll
        for (int half = 0; half < 2; ++half) {
            const int k0 = t8 * 64 + half * 32 + q * 8;
            u.w[half * 2 + 0] = pk_fp8(ldsf[k0 + 0][row] * inv, ldsf[k0 + 1][row] * inv,
                                       ldsf[k0 + 2][row] * inv, ldsf[k0 + 3][row] * inv);
            u.w[half * 2 + 1] = pk_fp8(ldsf[k0 + 4][row] * inv, ldsf[k0 + 5][row] * inv,
                                       ldsf[k0 + 6][row] * inv, ldsf[k0 + 7][row] * inv);
        }
        const int rgg = blockIdx.x * 2 + rgl;     // global row-group
        ((int4*)Xs)[rgg * 128 + cc] = u.v;
    }
}

// ---------------------------------------------------------------------------
// Kernel 2: software-pipelined persistent gram. Block k: tiles 6k..6k+5.
// Wave w: A rgs (w&1)*2..+1, B rgs (w>>1)*2..+1 of each 64x64 tile.
// B triple-buffered, 2-deep prefetch; A reloaded only on row change.
// No barriers in the loop; per-thread wsum; one block reduce at the end.
// ---------------------------------------------------------------------------
__global__ __launch_bounds__(256, 4)
void gram_lse_kernel(const int4* __restrict__ Xs, float* __restrict__ partials) {
    const int bk = blockIdx.x;
    const int tid = threadIdx.x;
    const int lane = tid & 63, w = tid >> 6;
    const int ga = (w & 1) * 2;                  // A rg offset within tile
    const int gb = (w >> 1) * 2;                 // B rg offset within tile
    const int quad = lane >> 4, colL = lane & 15;
    const float C = 14.426950408889634f;         // 10*log2(e)

    // decode first tile of the run, then the whole 6-tile list
    int L = bk * 6, I0 = 0;
    while (L >= 128 - I0) { L -= 128 - I0; ++I0; }
    int Is[6], Js[6];
    {
        int ii = I0, jj = I0 + L;
#pragma unroll
        for (int s = 0; s < 6; ++s) {
            Is[s] = ii; Js[s] = jj;
            if (++jj == 128) { ++ii; jj = ii; }
        }
    }

    // A fragments for the first row of the run
    int4 av[2][2];
    int IcurA = Is[0];
#pragma unroll
    for (int g = 0; g < 2; ++g)
#pragma unroll
        for (int t8 = 0; t8 < 2; ++t8)
            av[g][t8] = Xs[(Is[0] * 4 + ga + g) * 128 + t8 * 64 + lane];

    // B triple buffer, prefetch tiles 0 and 1
    int4 bv[3][2][2];
#pragma unroll
    for (int pf = 0; pf < 2; ++pf)
#pragma unroll
        for (int g = 0; g < 2; ++g)
#pragma unroll
            for (int t8 = 0; t8 < 2; ++t8)
                bv[pf][g][t8] = Xs[(Js[pf] * 4 + gb + g) * 128 + t8 * 64 + lane];

    float wsum = 0.f;
#pragma unroll
    for (int s = 0; s < 6; ++s) {
        // 2-deep prefetch of tile s+2's B fragments
        if (s + 2 < 6) {
#pragma unroll
            for (int g = 0; g < 2; ++g)
#pragma unroll
                for (int t8 = 0; t8 < 2; ++t8)
                    bv[(s + 2) % 3][g][t8] =
                        Xs[(Js[s + 2] * 4 + gb + g) * 128 + t8 * 64 + lane];
        }
        // A reload only when the run crosses a row boundary (~1x per block)
        if (Is[s] != IcurA) {
#pragma unroll
            for (int g = 0; g < 2; ++g)
#pragma unroll
                for (int t8 = 0; t8 < 2; ++t8)
                    av[g][t8] = Xs[(Is[s] * 4 + ga + g) * 128 + t8 * 64 + lane];
            IcurA = Is[s];
        }

        f32x4 acc[2][2];
#pragma unroll
        for (int i = 0; i < 2; ++i)
#pragma unroll
            for (int j = 0; j < 2; ++j) acc[i][j] = (f32x4){0.f, 0.f, 0.f, 0.f};
#pragma unroll
        for (int t = 0; t < 4; ++t) {            // K-steps of 32
            long aL[2], bL[2];
#pragma unroll
            for (int g = 0; g < 2; ++g) {
                aL[g] = ((const long*)&av[g][t >> 1])[t & 1];
                bL[g] = ((const long*)&bv[s % 3][g][t >> 1])[t & 1];
            }
#pragma unroll
            for (int i = 0; i < 2; ++i)
#pragma unroll
                for (int j = 0; j < 2; ++j)
                    acc[i][j] = __builtin_amdgcn_mfma_f32_16x16x32_fp8_fp8(
                        aL[i], bL[j], acc[i][j], 0, 0, 0);
        }

        // C/D: col=lane&15, row=(lane>>4)*4+reg (dtype-independent, verified)
        const bool diagT = (Is[s] == Js[s]);
        float lsum = 0.f;
#pragma unroll
        for (int i = 0; i < 2; ++i) {
            const int rbase = (ga + i) * 16 + quad * 4;   // row within tile
#pragma unroll
            for (int j = 0; j < 2; ++j) {
                const int cbase = (gb + j) * 16 + colL;   // col within tile
#pragma unroll
                for (int g = 0; g < 4; ++g) {
                    if (diagT && (rbase + g == cbase)) continue;
                    lsum += EXP2F(fmaf(C, acc[i][j][g], -C));
                }
            }
        }
        wsum += diagT ? lsum : 2.0f * lsum;      // symmetry weight
    }

#pragma unroll
    for (int o = 32; o > 0; o >>= 1) wsum += __shfl_down(wsum, o, 64);
    __shared__ float red[4];
    if (lane == 0) red[w] = wsum;
    __syncthreads();
    if (tid == 0) partials[bk] = red[0] + red[1] + red[2] + red[3];
}

// ---------------------------------------------------------------------------
// Kernel 3: out = 10 + ln(sum of 1376 partials), f64 accumulation.
// ---------------------------------------------------------------------------
__global__ __launch_bounds__(256)
void final_kernel(const float* __restrict__ partials, float* __restrict__ out) {
    double s = 0.0;
    for (int i = threadIdx.x; i < NPBLK; i += 256) s += (double)partials[i];
#pragma unroll
    for (int o = 32; o > 0; o >>= 1) s += __shfl_down(s, o, 64);
    __shared__ double red[4];
    if ((threadIdx.x & 63) == 0) red[threadIdx.x >> 6] = s;
    __syncthreads();
    if (threadIdx.x == 0)
        out[0] = (float)(10.0 + log(red[0] + red[1] + red[2] + red[3]));
}

extern "C" void kernel_launch(void* const* d_in, const int* in_sizes, int n_in,
                              void* d_out, int out_size, void* d_ws, size_t ws_size,
                              hipStream_t stream) {
    const float* x = (const float*)d_in[0];
    float* out = (float*)d_out;
    float* partials = (float*)d_ws;                         // 1376 floats
    unsigned char* Xs = (unsigned char*)d_ws + 131072;      // 1MB fp8 X̂

    normalize_kernel<<<256, 256, 0, stream>>>(x, Xs);
    gram_lse_kernel<<<NPBLK, 256, 0, stream>>>((const int4*)Xs, partials);
    final_kernel<<<1, 256, 0, stream>>>(partials, out);
}